// Round 1
// baseline (119.329 us; speedup 1.0000x reference)
//
#include <hip/hip_runtime.h>
#include <math.h>

#define NN 256
#define AA 20
#define UD 624
#define SS 768
#define NAU (AA*UD)          // 12480
#define PI_D 3.14159265358979323846

// ---------------- transpose img [B,N,N] -> imgT [N*N] float4 (batch inner) ----
__global__ void k_transpose(const float* __restrict__ img, float4* __restrict__ imgT) {
    int idx = blockIdx.x * 256 + threadIdx.x;   // 0..65535
    float4 v;
    v.x = img[idx];
    v.y = img[65536 + idx];
    v.z = img[131072 + idx];
    v.w = img[196608 + idx];
    imgT[idx] = v;
}

// ---------------- filter kernel hh[n], n=0..623 ------------------------------
// hh[n] = (1/2048^2) * sum_{k=1}^{1023} k*(1+cos(pi*k/1024))*cos(pi*(k*n mod 2048)/1024)
__global__ void k_hh(float* __restrict__ hh) {
    __shared__ double red[256];
    const int n = blockIdx.x;           // 0..623
    const int tid = threadIdx.x;
    double acc = 0.0;
    for (int k = 1 + tid; k < 1024; k += 256) {
        float a1 = 1.0f + cosf((float)PI_D * (float)k * (1.0f/1024.0f));
        int m = (k * n) & 2047;
        float c2 = cosf((float)PI_D * (float)m * (1.0f/1024.0f));
        acc += (double)((float)k * a1 * c2);
    }
    red[tid] = acc;
    __syncthreads();
    for (int s = 128; s > 0; s >>= 1) {
        if (tid < s) red[tid] += red[tid + s];
        __syncthreads();
    }
    if (tid == 0) hh[n] = (float)(red[0] * (1.0 / (2048.0 * 2048.0)));
}

// ---------------- forward project + residual + cosine weight -> g ------------
// one 64-thread block per ray (a,u); 12 samples/lane; batches via float4
__global__ __launch_bounds__(64) void k_forward(const float4* __restrict__ imgT,
                                                const float* __restrict__ proj,
                                                float* __restrict__ g) {
    const int blk = blockIdx.x;            // a*UD + u
    const int a = blk / UD;
    const int u = blk - a * UD;
    const int tid = threadIdx.x;

    const float theta = (float)(((double)a + 0.5) * (2.0 * PI_D / (double)AA));
    float sn, cs;
    sincosf(theta, &sn, &cs);
    const float uc = (float)(-60.0 + ((double)u + 0.5) * (120.0 / 624.0));

    const float sx = 59.0f * cs, sy = 59.0f * sn;
    const float px = -49.0f * cs - uc * sn;
    const float py = -49.0f * sn + uc * cs;
    const float rx = px - sx, ry = py - sy;
    const float length = sqrtf(rx * rx + ry * ry);

    float ax = 0.f, ay = 0.f, az = 0.f, aw = 0.f;

    for (int s = tid; s < SS; s += 64) {
        float t = ((float)s + 0.5f) * (1.0f / 768.0f);
        float x = sx + t * rx;
        float y = sy + t * ry;
        float gx = (x + 20.0f) * 6.4f - 0.5f;
        float gy = (y + 20.0f) * 6.4f - 0.5f;
        float fgx = floorf(gx), fgy = floorf(gy);
        float fx = gx - fgx, fy = gy - fgy;
        int i0 = (int)fgx, j0 = (int)fgy;
        int i1 = i0 + 1, j1 = j0 + 1;
        float wx0 = (i0 >= 0 && i0 < NN) ? (1.0f - fx) : 0.0f;
        float wx1 = (i1 >= 0 && i1 < NN) ? fx : 0.0f;
        float wy0 = (j0 >= 0 && j0 < NN) ? (1.0f - fy) : 0.0f;
        float wy1 = (j1 >= 0 && j1 < NN) ? fy : 0.0f;
        int ic0 = min(max(i0, 0), NN - 1), ic1 = min(max(i1, 0), NN - 1);
        int jc0 = min(max(j0, 0), NN - 1), jc1 = min(max(j1, 0), NN - 1);
        float4 c00 = imgT[ic0 * NN + jc0];
        float4 c10 = imgT[ic1 * NN + jc0];
        float4 c01 = imgT[ic0 * NN + jc1];
        float4 c11 = imgT[ic1 * NN + jc1];
        float w00 = wx0 * wy0, w10 = wx1 * wy0, w01 = wx0 * wy1, w11 = wx1 * wy1;
        ax += w00 * c00.x + w10 * c10.x + w01 * c01.x + w11 * c11.x;
        ay += w00 * c00.y + w10 * c10.y + w01 * c01.y + w11 * c11.y;
        az += w00 * c00.z + w10 * c10.z + w01 * c01.z + w11 * c11.z;
        aw += w00 * c00.w + w10 * c10.w + w01 * c01.w + w11 * c11.w;
    }

    for (int off = 32; off > 0; off >>= 1) {
        ax += __shfl_down(ax, off);
        ay += __shfl_down(ay, off);
        az += __shfl_down(az, off);
        aw += __shfl_down(aw, off);
    }

    if (tid == 0) {
        const float scale = length * (1.0f / 768.0f);
        const float wdet = 108.0f / sqrtf(108.0f * 108.0f + uc * uc);
        g[0 * NAU + blk] = (proj[0 * NAU + blk] - ax * scale) * wdet;
        g[1 * NAU + blk] = (proj[1 * NAU + blk] - ay * scale) * wdet;
        g[2 * NAU + blk] = (proj[2 * NAU + blk] - az * scale) * wdet;
        g[3 * NAU + blk] = (proj[3 * NAU + blk] - aw * scale) * wdet;
    }
}

// ---------------- direct convolution: q[row,j] = sum_i g[row,i]*hh[|j-i|] ----
__global__ __launch_bounds__(640) void k_conv(const float* __restrict__ g,
                                              const float* __restrict__ hh,
                                              float* __restrict__ q) {
    __shared__ float sg[UD];
    __shared__ float sh[UD];
    const int row = blockIdx.x;        // b*AA + a, 0..79
    const int tid = threadIdx.x;
    if (tid < UD) {
        sg[tid] = g[row * UD + tid];
        sh[tid] = hh[tid];
    }
    __syncthreads();
    if (tid < UD) {
        float acc = 0.0f;
        for (int i = 0; i < UD; ++i) {
            int d = tid - i;
            d = d < 0 ? -d : d;
            acc += sg[i] * sh[d];
        }
        q[row * UD + tid] = acc;
    }
}

// ---------------- back-projection -------------------------------------------
__global__ __launch_bounds__(256) void k_bp(const float* __restrict__ q,
                                            float* __restrict__ out) {
    __shared__ float scs[AA], ssn[AA];
    const int tid = threadIdx.x;
    if (tid < AA) {
        float th = (float)(((double)tid + 0.5) * (2.0 * PI_D / (double)AA));
        float s, c;
        sincosf(th, &s, &c);
        scs[tid] = c;
        ssn[tid] = s;
    }
    __syncthreads();

    const int p = blockIdx.x * 256 + tid;   // 0..262143
    const int b = p >> 16;
    const int rem = p & 65535;
    const int i = rem >> 8;
    const int j = rem & 255;

    const float X = -20.0f + ((float)i + 0.5f) * 0.15625f;
    const float Y = -20.0f + ((float)j + 0.5f) * 0.15625f;

    const float uc0 = (float)(-60.0 + 0.5 * (120.0 / 624.0));
    const float duf = (float)(120.0 / 624.0);

    const float* qb = q + b * AA * UD;
    float acc = 0.0f;
    for (int a = 0; a < AA; ++a) {
        float cs = scs[a], sn = ssn[a];
        float t = 59.0f - (X * cs + Y * sn);
        float uu = 108.0f * (Y * cs - X * sn) / t;
        float k = (uu - uc0) / duf;
        float fk0 = floorf(k);
        float fk = k - fk0;
        int ik = (int)fk0;
        const float* qr = qb + a * UD;
        float v0 = ((unsigned)ik < (unsigned)UD) ? qr[ik] : 0.0f;
        float v1 = ((unsigned)(ik + 1) < (unsigned)UD) ? qr[ik + 1] : 0.0f;
        float val = v0 * (1.0f - fk) + v1 * fk;
        float w = 59.0f / t;
        acc += w * w * val;
    }
    out[p] = (0.5f * (float)(2.0 * PI_D / (double)AA)) * acc;
}

extern "C" void kernel_launch(void* const* d_in, const int* in_sizes, int n_in,
                              void* d_out, int out_size, void* d_ws, size_t ws_size,
                              hipStream_t stream) {
    const float* img  = (const float*)d_in[0];   // [4,256,256]
    const float* proj = (const float*)d_in[1];   // [4,20,624]
    float* out = (float*)d_out;                  // [4,256,256]

    char* ws = (char*)d_ws;
    float4* imgT = (float4*)ws;                          // 1 MiB
    float*  g    = (float*)(ws + (1 << 20));             // 199680 B
    float*  q    = (float*)(ws + (1 << 20) + 199680);    // 199680 B
    float*  hh   = (float*)(ws + (1 << 20) + 2 * 199680);// 2496 B

    k_transpose<<<256, 256, 0, stream>>>(img, imgT);
    k_hh<<<UD, 256, 0, stream>>>(hh);
    k_forward<<<NAU, 64, 0, stream>>>(imgT, proj, g);
    k_conv<<<AA * 4, 640, 0, stream>>>(g, hh, q);
    k_bp<<<1024, 256, 0, stream>>>(q, out);
}

// Round 2
// 114.268 us; speedup vs baseline: 1.0443x; 1.0443x over previous
//
#include <hip/hip_runtime.h>
#include <math.h>

#define NN 256
#define AA 20
#define UD 624
#define SS 768
#define NAU (AA*UD)          // 12480
#define PI_D 3.14159265358979323846

// ---------------- prep: imgA [i][j] float4, imgB [j][i] float4, hh filter ----
// blocks [0,256): layout A ; [256,512): layout B ; [512,1136): hh rows
__global__ __launch_bounds__(256) void k_prep(const float* __restrict__ img,
                                              float4* __restrict__ pixA,
                                              float4* __restrict__ pixB,
                                              float* __restrict__ hh) {
    __shared__ double red[256];
    const int blk = blockIdx.x;
    const int tid = threadIdx.x;
    if (blk < 256) {
        int idx = blk * 256 + tid;         // i*256+j
        float4 v;
        v.x = img[idx];
        v.y = img[65536 + idx];
        v.z = img[131072 + idx];
        v.w = img[196608 + idx];
        pixA[idx] = v;
    } else if (blk < 512) {
        int oidx = (blk - 256) * 256 + tid; // j*256+i
        int j = oidx >> 8, i = oidx & 255;
        int idx = i * 256 + j;
        float4 v;
        v.x = img[idx];
        v.y = img[65536 + idx];
        v.z = img[131072 + idx];
        v.w = img[196608 + idx];
        pixB[oidx] = v;
    } else {
        const int n = blk - 512;           // 0..623
        double acc = 0.0;
        for (int k = 1 + tid; k < 1024; k += 256) {
            float a1 = 1.0f + cosf((float)PI_D * (float)k * (1.0f/1024.0f));
            int m = (k * n) & 2047;
            float c2 = cosf((float)PI_D * (float)m * (1.0f/1024.0f));
            acc += (double)((float)k * a1 * c2);
        }
        red[tid] = acc;
        __syncthreads();
        for (int s = 128; s > 0; s >>= 1) {
            if (tid < s) red[tid] += red[tid + s];
            __syncthreads();
        }
        if (tid == 0) hh[n] = (float)(red[0] * (1.0 / (2048.0 * 2048.0)));
    }
}

// ---------------- forward project + residual + cosine weight -> g ------------
// 4 rays per 256-thread block (one wave per ray); per-ray layout choice.
__global__ __launch_bounds__(256) void k_forward(const float4* __restrict__ pixA,
                                                 const float4* __restrict__ pixB,
                                                 const float* __restrict__ proj,
                                                 float* __restrict__ g) {
    const int wid = threadIdx.x >> 6;
    const int lane = threadIdx.x & 63;
    const int ray = blockIdx.x * 4 + wid;   // a*UD + u
    const int a = ray / UD;
    const int u = ray - a * UD;

    const float theta = (float)(((double)a + 0.5) * (2.0 * PI_D / (double)AA));
    float sn, cs;
    sincosf(theta, &sn, &cs);
    const float uc = (float)(-60.0 + ((double)u + 0.5) * (120.0 / 624.0));

    const float sx = 59.0f * cs, sy = 59.0f * sn;
    const float rx = -108.0f * cs - uc * sn;
    const float ry = -108.0f * sn + uc * cs;
    const float length = sqrtf(rx * rx + ry * ry);

    // gx(s) = basex + s*stepx   (fractional index coords)
    const float stepx = rx * (6.4f / 768.0f);
    const float basex = (sx + rx * (0.5f / 768.0f) + 20.0f) * 6.4f - 0.5f;
    const float stepy = ry * (6.4f / 768.0f);
    const float basey = (sy + ry * (0.5f / 768.0f) + 20.0f) * 6.4f - 0.5f;

    // pick layout so the fast-moving coordinate is the contiguous (inner) dim
    const bool useB = fabsf(stepx) > fabsf(stepy);
    const float4* __restrict__ im = useB ? pixB : pixA;
    const float bi = useB ? basex : basey;
    const float si = useB ? stepx : stepy;
    const float bo = useB ? basey : basex;
    const float so = useB ? stepy : stepx;

    float ax = 0.f, ay = 0.f, az = 0.f, aw = 0.f;

    for (int s = lane; s < SS; s += 64) {
        float gi = fmaf((float)s, si, bi);
        float go = fmaf((float)s, so, bo);
        float fgi = floorf(gi), fgo = floorf(go);
        float fi = gi - fgi, fo = go - fgo;
        int i0 = (int)fgi, o0 = (int)fgo;
        int i1 = i0 + 1, o1 = o0 + 1;
        float wi0 = (i0 >= 0 && i0 < NN) ? (1.0f - fi) : 0.0f;
        float wi1 = (i1 >= 0 && i1 < NN) ? fi : 0.0f;
        float wo0 = (o0 >= 0 && o0 < NN) ? (1.0f - fo) : 0.0f;
        float wo1 = (o1 >= 0 && o1 < NN) ? fo : 0.0f;
        int ic0 = min(max(i0, 0), NN - 1), ic1 = min(max(i1, 0), NN - 1);
        int oc0 = min(max(o0, 0), NN - 1), oc1 = min(max(o1, 0), NN - 1);
        const float4 c00 = im[oc0 * NN + ic0];
        const float4 c10 = im[oc0 * NN + ic1];
        const float4 c01 = im[oc1 * NN + ic0];
        const float4 c11 = im[oc1 * NN + ic1];
        float w00 = wi0 * wo0, w10 = wi1 * wo0, w01 = wi0 * wo1, w11 = wi1 * wo1;
        ax += w00 * c00.x + w10 * c10.x + w01 * c01.x + w11 * c11.x;
        ay += w00 * c00.y + w10 * c10.y + w01 * c01.y + w11 * c11.y;
        az += w00 * c00.z + w10 * c10.z + w01 * c01.z + w11 * c11.z;
        aw += w00 * c00.w + w10 * c10.w + w01 * c01.w + w11 * c11.w;
    }

    for (int off = 32; off > 0; off >>= 1) {
        ax += __shfl_down(ax, off);
        ay += __shfl_down(ay, off);
        az += __shfl_down(az, off);
        aw += __shfl_down(aw, off);
    }

    if (lane == 0) {
        const float scale = length * (1.0f / 768.0f);
        const float wdet = 108.0f / sqrtf(108.0f * 108.0f + uc * uc);
        g[0 * NAU + ray] = (proj[0 * NAU + ray] - ax * scale) * wdet;
        g[1 * NAU + ray] = (proj[1 * NAU + ray] - ay * scale) * wdet;
        g[2 * NAU + ray] = (proj[2 * NAU + ray] - az * scale) * wdet;
        g[3 * NAU + ray] = (proj[3 * NAU + ray] - aw * scale) * wdet;
    }
}

// ---------------- direct convolution: q[row,j] = sum_i g[row,i]*hh[|j-i|] ----
// two monotone segments; hh[t] wave-uniform (scalar load), g stride-1 in LDS.
__global__ __launch_bounds__(128) void k_conv(const float* __restrict__ g,
                                              const float* __restrict__ hh,
                                              float* __restrict__ q) {
    __shared__ float sgp[752];          // 64 zeros | 624 row | 64 zeros
    const int row = blockIdx.x / 5;     // b*AA + a, 0..79
    const int tile = blockIdx.x % 5;    // j-tile of 128
    const int tid = threadIdx.x;

    for (int k = tid; k < 752; k += 128) {
        sgp[k] = (k >= 64 && k < 64 + UD) ? g[row * UD + (k - 64)] : 0.0f;
    }
    __syncthreads();

    const int j = tile * 128 + tid;
    const int jc = min(j, UD - 1);
    int wbase = tile * 128 + (tid & 64);                 // wave's min j
    wbase = __builtin_amdgcn_readfirstlane(wbase);
    const int tmax1 = min(wbase + 63, UD - 1);
    const int tmax2 = UD - 1 - wbase;

    float acc = 0.0f;
    for (int t = 0; t <= tmax1; ++t)                     // i = j - t
        acc += hh[t] * sgp[64 + jc - t];
    for (int t = 1; t <= tmax2; ++t)                     // i = j + t
        acc += hh[t] * sgp[64 + jc + t];

    if (j < UD) q[row * UD + j] = acc;
}

// ---------------- back-projection -------------------------------------------
__global__ __launch_bounds__(256) void k_bp(const float* __restrict__ q,
                                            float* __restrict__ out) {
    __shared__ float scs[AA], ssn[AA];
    const int tid = threadIdx.x;
    if (tid < AA) {
        float th = (float)(((double)tid + 0.5) * (2.0 * PI_D / (double)AA));
        float s, c;
        sincosf(th, &s, &c);
        scs[tid] = c;
        ssn[tid] = s;
    }
    __syncthreads();

    const int p = blockIdx.x * 256 + tid;   // 0..262143
    const int b = p >> 16;
    const int rem = p & 65535;
    const int i = rem >> 8;
    const int j = rem & 255;

    const float X = -20.0f + ((float)i + 0.5f) * 0.15625f;
    const float Y = -20.0f + ((float)j + 0.5f) * 0.15625f;

    const float uc0 = (float)(-60.0 + 0.5 * (120.0 / 624.0));
    const float duf = (float)(120.0 / 624.0);

    const float* __restrict__ qb = q + b * AA * UD;
    float acc = 0.0f;
#pragma unroll
    for (int a = 0; a < AA; ++a) {
        float cs = scs[a], sn = ssn[a];
        float t = 59.0f - (X * cs + Y * sn);
        float uu = 108.0f * (Y * cs - X * sn) / t;
        float k = (uu - uc0) / duf;
        float fk0 = floorf(k);
        float fk = k - fk0;
        int ik = (int)fk0;
        const float* qr = qb + a * UD;
        float v0 = ((unsigned)ik < (unsigned)UD) ? qr[ik] : 0.0f;
        float v1 = ((unsigned)(ik + 1) < (unsigned)UD) ? qr[ik + 1] : 0.0f;
        float val = v0 * (1.0f - fk) + v1 * fk;
        float w = 59.0f / t;
        acc += w * w * val;
    }
    out[p] = (0.5f * (float)(2.0 * PI_D / (double)AA)) * acc;
}

extern "C" void kernel_launch(void* const* d_in, const int* in_sizes, int n_in,
                              void* d_out, int out_size, void* d_ws, size_t ws_size,
                              hipStream_t stream) {
    const float* img  = (const float*)d_in[0];   // [4,256,256]
    const float* proj = (const float*)d_in[1];   // [4,20,624]
    float* out = (float*)d_out;                  // [4,256,256]

    char* ws = (char*)d_ws;
    float4* pixA = (float4*)ws;                              // 1 MiB
    float4* pixB = (float4*)(ws + (1 << 20));                // 1 MiB
    float*  g    = (float*)(ws + (2 << 20));                 // 199680 B
    float*  q    = (float*)(ws + (2 << 20) + 199680);        // 199680 B
    float*  hh   = (float*)(ws + (2 << 20) + 2 * 199680);    // 2496 B

    k_prep<<<1136, 256, 0, stream>>>(img, pixA, pixB, hh);
    k_forward<<<NAU / 4, 256, 0, stream>>>(pixA, pixB, proj, g);
    k_conv<<<80 * 5, 128, 0, stream>>>(g, hh, q);
    k_bp<<<1024, 256, 0, stream>>>(q, out);
}